// Round 5
// baseline (771.612 us; speedup 1.0000x reference)
//
#include <hip/hip_runtime.h>
#include <math.h>

typedef _Float16 f16;
typedef _Float16 f16x8 __attribute__((ext_vector_type(8)));
typedef float f32x4 __attribute__((ext_vector_type(4)));
typedef float f32x16 __attribute__((ext_vector_type(16)));

#define T_ 8
#define NNODES 100000
#define F_ 128
#define B_ 4096
#define S1_ 5
#define S2_ 2
#define H1_ 512
#define H2_ 64
#define O_ 32
#define M1 (B_ + B_*S1_)      /* 24576 rows: [h0-block | h1-block] */
#define K1 (2*F_)             /* 256: [h | agg] */
#define NZ 12                 /* z<8 -> (t=z,c=0); z>=8 -> (t=2*(z-8),c=1) */

__device__ __forceinline__ float wsum64(float v) {
#pragma unroll
  for (int o = 32; o > 0; o >>= 1) v += __shfl_xor(v, o, 64);
  return v;
}

// ---------------------------------------------------------------- pos table
__global__ __launch_bounds__(512) void postab_kernel(float* __restrict__ postab) {
  int i = threadIdx.x;
  int p = i >> 6, d = i & 63;
  double ang = (double)p / pow(10000.0, (2.0 * (double)(d >> 1)) / 64.0);
  postab[i] = (float)((d & 1) ? cos(ang) : sin(ang));
}

// ---------------------------------------------------------------- gemm1 weight limbs
// Bt[c][n=512][k=256] f16; k<128 from Wself1, k>=128 from Wnbr1 (transposed)
__global__ __launch_bounds__(256)
void prep_w(const float* __restrict__ Ws1, const float* __restrict__ Wn1,
            f16* __restrict__ Bth, f16* __restrict__ Btl) {
  const int bid = blockIdx.x;            // 0..1023
  const int c = bid >> 9, n = bid & 511;
  const int k = threadIdx.x;             // 0..255
  float wv = (k < F_) ? Ws1[((size_t)c * F_ + k) * H1_ + n]
                      : Wn1[((size_t)c * F_ + (k - F_)) * H1_ + n];
  f16 hi = (f16)wv;
  f16 lo = (f16)((wv - (float)hi) * 2048.0f);
  size_t o = ((size_t)c * H1_ + n) * K1 + k;
  Bth[o] = hi; Btl[o] = lo;
}

// ---------------------------------------------------------------- gemm2 weight limbs
// B2t[c][n=64][k=1024] f16; k<512: Ws2[k][n]; k>=512: 0.2f*Wn2[k-512][n]
__global__ __launch_bounds__(256)
void prep_w2(const float* __restrict__ Ws2, const float* __restrict__ Wn2,
             f16* __restrict__ B2h, f16* __restrict__ B2l) {
  const int c = blockIdx.x >> 6, n = blockIdx.x & 63;
#pragma unroll
  for (int q = 0; q < 4; ++q) {
    const int k = q * 256 + threadIdx.x;
    float v = (k < H1_) ? Ws2[((size_t)c * H1_ + k) * H2_ + n]
                        : 0.2f * Wn2[((size_t)c * H1_ + (k - H1_)) * H2_ + n];
    f16 hi = (f16)v;
    f16 lo = (f16)((v - (float)hi) * 2048.0f);
    size_t o = ((size_t)c * H2_ + n) * 1024 + k;
    B2h[o] = hi; B2l[o] = lo;
  }
}

// ---------------------------------------------------------------- gather+agg
__global__ __launch_bounds__(256) void gather_kernel(
    const int* __restrict__ nodes, const int* __restrict__ hop1,
    const int* __restrict__ hop2, const float* __restrict__ x,
    f16* __restrict__ Ah, f16* __restrict__ Al)
{
  const int t = blockIdx.y;
  const int r = blockIdx.x * 4 + (threadIdx.x >> 6);
  const int lane = threadIdx.x & 63;
  const int fo = (lane & 31) << 2;
  const bool hpart = lane < 32;
  const float* xt = x + (size_t)t * NNODES * F_;
  float4 v;
  if (r < B_) {
    if (hpart) {
      v = *(const float4*)(xt + (size_t)nodes[r] * F_ + fo);
    } else {
      v = make_float4(0.f, 0.f, 0.f, 0.f);
#pragma unroll
      for (int s = 0; s < S1_; ++s) {
        int idx = hop1[t * (B_ * S1_) + r * S1_ + s];
        float4 u = *(const float4*)(xt + (size_t)idx * F_ + fo);
        v.x += u.x; v.y += u.y; v.z += u.z; v.w += u.w;
      }
      v.x /= 5.0f; v.y /= 5.0f; v.z /= 5.0f; v.w /= 5.0f;
    }
  } else {
    const int j = r - B_;
    if (hpart) {
      v = *(const float4*)(xt + (size_t)hop1[t * (B_ * S1_) + j] * F_ + fo);
    } else {
      v = make_float4(0.f, 0.f, 0.f, 0.f);
#pragma unroll
      for (int s = 0; s < S2_; ++s) {
        int idx = hop2[t * (B_ * S1_ * S2_) + j * S2_ + s];
        float4 u = *(const float4*)(xt + (size_t)idx * F_ + fo);
        v.x += u.x; v.y += u.y; v.z += u.z; v.w += u.w;
      }
      v.x *= 0.5f; v.y *= 0.5f; v.z *= 0.5f; v.w *= 0.5f;
    }
  }
  union { f16 h[4]; uint2 u; } H, L;
  float vv[4] = {v.x, v.y, v.z, v.w};
#pragma unroll
  for (int e = 0; e < 4; ++e) {
    f16 hi = (f16)vv[e];
    H.h[e] = hi;
    L.h[e] = (f16)((vv[e] - (float)hi) * 2048.0f);
  }
  const size_t base = ((size_t)t * M1 + r) * K1 + 4 * lane;
  *(uint2*)(Ah + base) = H.u;
  *(uint2*)(Al + base) = L.u;
}

// ---------------------------------------------------------------- GEMM1 (MFMA 32x32x16 fp16x3) + spike
// 128x128 tile, 4 waves (64x64 each as 2x2 of 32x32), BK=16, dbuf 32KB -> 5 blocks/CU.
__global__ __launch_bounds__(256)
void gemm1_mfma(const f16* __restrict__ Ah, const f16* __restrict__ Al,
                const f16* __restrict__ Bth, const f16* __restrict__ Btl,
                unsigned char* __restrict__ Sbase)
{
  // bijective XCD swizzle: 9216 blocks = 8 XCDs x 1152.
  const int hid = blockIdx.x + 4 * blockIdx.y + 768 * blockIdx.z;
  const int xcd = hid & 7, ii = hid >> 3;
  const int nblk = ii & 3;                  // N-block 0..3
  const int pair = xcd * 288 + (ii >> 2);   // 0..2303 = (yblk,z) pair
  const int yblk = pair % 192;
  const int z    = pair / 192;

  const int t = (z < 8) ? z : 2 * (z - 8);
  const int c = (z < 8) ? 0 : 1;
  const int m0 = yblk * 128;
  const int n0 = nblk * 128;
  const int tid = threadIdx.x;
  const int lane = tid & 63;
  const int w = tid >> 6;
  const int wr = w >> 1, wc = w & 1;

  __shared__ f16 lds[2][4][2][128][8];   // [buf][tile 0:Ah 1:Al 2:Bh 3:Bl][k2][row][8] = 32KB

  const f16* tb0 = Ah  + (size_t)t * M1 * K1;
  const f16* tb1 = Al  + (size_t)t * M1 * K1;
  const f16* tb2 = Bth + (size_t)c * H1_ * K1;
  const f16* tb3 = Btl + (size_t)c * H1_ * K1;
  const f16* tbs[4] = {tb0, tb1, tb2, tb3};

  // 1024 16B-units per buffer; unit u = (q*4+w)*64 + lane -> LDS byte u*16
  const f16* srcp[4];
#pragma unroll
  for (int q = 0; q < 4; ++q) {
    const int u = (q * 4 + w) * 64 + lane;
    const int tile = u >> 8, rem = u & 255;
    const int k2 = rem >> 7, row = rem & 127;
    const int rbase = (tile < 2) ? (m0 + row) : (n0 + row);
    srcp[q] = tbs[tile] + (size_t)rbase * K1 + k2 * 8;
  }

  auto stage = [&](int buf) {
#pragma unroll
    for (int q = 0; q < 4; ++q) {
      __builtin_amdgcn_global_load_lds(
          (const __attribute__((address_space(1))) void*)srcp[q],
          (__attribute__((address_space(3))) void*)((char*)lds + buf * 16384 + (q * 4 + w) * 1024),
          16, 0, 0);
      srcp[q] += 16;   // next 16-k chunk
    }
  };

  f32x16 accm[2][2], accc[2][2];
#pragma unroll
  for (int i = 0; i < 2; ++i)
#pragma unroll
    for (int j = 0; j < 2; ++j) {
      accm[i][j] = (f32x16)(0.f);
      accc[i][j] = (f32x16)(0.f);
    }

  const int kg = lane >> 5;      // k2 half 0..1
  const int lr = lane & 31;      // row/col within 32

  stage(0);
  __syncthreads();   // buf0 ready

#pragma unroll 1
  for (int kt = 0; kt < 16; ++kt) {
    const int cur = kt & 1;
    if (kt < 15) stage(cur ^ 1);   // prefetch next tile; hides under MFMA below

    f16x8 ah[2], al[2], bh[2], bl[2];
#pragma unroll
    for (int i = 0; i < 2; ++i) {
      ah[i] = *(const f16x8*)&lds[cur][0][kg][wr * 64 + i * 32 + lr][0];
      al[i] = *(const f16x8*)&lds[cur][1][kg][wr * 64 + i * 32 + lr][0];
    }
#pragma unroll
    for (int j = 0; j < 2; ++j) {
      bh[j] = *(const f16x8*)&lds[cur][2][kg][wc * 64 + j * 32 + lr][0];
      bl[j] = *(const f16x8*)&lds[cur][3][kg][wc * 64 + j * 32 + lr][0];
    }
#pragma unroll
    for (int j = 0; j < 2; ++j)
#pragma unroll
      for (int i = 0; i < 2; ++i) {
        accm[i][j] = __builtin_amdgcn_mfma_f32_32x32x16_f16(ah[i], bh[j], accm[i][j], 0, 0, 0);
        accc[i][j] = __builtin_amdgcn_mfma_f32_32x32x16_f16(ah[i], bl[j], accc[i][j], 0, 0, 0);
        accc[i][j] = __builtin_amdgcn_mfma_f32_32x32x16_f16(al[i], bh[j], accc[i][j], 0, 0, 0);
      }
    __syncthreads();   // drains prefetch + protects buf reuse
  }

  // epilogue: C/D 32x32: col=lane&31, row=(r&3)+8*(r>>2)+4*(lane>>5)
  unsigned char* S = Sbase + (size_t)z * M1 * H1_;
#pragma unroll
  for (int i = 0; i < 2; ++i)
#pragma unroll
    for (int j = 0; j < 2; ++j) {
      const int n = n0 + wc * 64 + j * 32 + lr;
#pragma unroll
      for (int r = 0; r < 16; ++r) {
        const int m = m0 + wr * 64 + i * 32 + (r & 3) + 8 * (r >> 2) + 4 * kg;
        float v = accm[i][j][r] + accc[i][j][r] * 4.8828125e-4f;
        S[(size_t)m * H1_ + n] = (v >= 1.0f) ? 1 : 0;
      }
    }
}

// ---------------------------------------------------------------- A2 build (S -> f16 exact)
__global__ __launch_bounds__(256)
void prep_a2(const unsigned char* __restrict__ Sbase, f16* __restrict__ A2)
{
  const int z = blockIdx.y;
  const int r = blockIdx.x * 4 + (threadIdx.x >> 6);
  const int lane = threadIdx.x & 63;
  const unsigned char* Sz = Sbase + (size_t)z * M1 * H1_;
  f16* A2row = A2 + ((size_t)z * B_ + r) * 1024;

  unsigned long long u = *(const unsigned long long*)(Sz + (size_t)r * H1_ + lane * 8);
  union { f16 h[8]; uint4 v; } P;
#pragma unroll
  for (int e = 0; e < 8; ++e) P.h[e] = (f16)(int)((u >> (8 * e)) & 0xFFull);
  *(uint4*)(A2row + lane * 8) = P.v;

  unsigned int q[8] = {0, 0, 0, 0, 0, 0, 0, 0};
#pragma unroll
  for (int s = 0; s < S1_; ++s) {
    unsigned long long us = *(const unsigned long long*)(
        Sz + ((size_t)B_ + (size_t)r * S1_ + s) * H1_ + lane * 8);
#pragma unroll
    for (int e = 0; e < 8; ++e) q[e] += (unsigned)((us >> (8 * e)) & 0xFFull);
  }
#pragma unroll
  for (int e = 0; e < 8; ++e) P.h[e] = (f16)(int)q[e];
  *(uint4*)(A2row + H1_ + lane * 8) = P.v;
}

// ---------------------------------------------------------------- GEMM2 (MFMA, exact-A 2-limb B) + spike
__global__ __launch_bounds__(256)
void gemm2_mfma(const f16* __restrict__ A2,
                const f16* __restrict__ B2h, const f16* __restrict__ B2l,
                unsigned char* __restrict__ outsbase)
{
  const int z = blockIdx.y;
  const int c = (z < 8) ? 0 : 1;
  const int m0 = blockIdx.x * 128;
  const int tid = threadIdx.x;
  const int lane = tid & 63;
  const int wv = tid >> 6;

  __shared__ f16 lds2[2][8192];   // [buf][A:4096 | Bh:2048 | Bl:2048] f16 = 32 KB

  const f16* Az  = A2 + (size_t)z * B_ * 1024;
  const f16* Bhc = B2h + (size_t)c * H2_ * 1024;
  const f16* Blc = B2l + (size_t)c * H2_ * 1024;

  const f16* srcp[4];
#pragma unroll
  for (int q = 0; q < 4; ++q) {
    const int u = q * 256 + tid;
    if (u < 512) {
      const int k8 = u >> 7, row = u & 127;
      srcp[q] = Az + (size_t)(m0 + row) * 1024 + k8 * 8;
    } else if (u < 768) {
      const int v = u - 512, k8 = v >> 6, row = v & 63;
      srcp[q] = Bhc + (size_t)row * 1024 + k8 * 8;
    } else {
      const int v = u - 768, k8 = v >> 6, row = v & 63;
      srcp[q] = Blc + (size_t)row * 1024 + k8 * 8;
    }
  }

  auto stage = [&](int buf) {
#pragma unroll
    for (int q = 0; q < 4; ++q) {
      __builtin_amdgcn_global_load_lds(
          (const __attribute__((address_space(1))) void*)srcp[q],
          (__attribute__((address_space(3))) void*)((char*)lds2 + buf * 16384 + (q * 4 + wv) * 1024),
          16, 0, 0);
      srcp[q] += 32;
    }
  };

  f32x4 acch[2][4], accl[2][4];
#pragma unroll
  for (int i = 0; i < 2; ++i)
#pragma unroll
    for (int j = 0; j < 4; ++j) {
      acch[i][j] = (f32x4){0.f, 0.f, 0.f, 0.f};
      accl[i][j] = (f32x4){0.f, 0.f, 0.f, 0.f};
    }

  const int kg = lane >> 4;
  const int lr = lane & 15;

  stage(0);
  __syncthreads();

#pragma unroll 1
  for (int kt = 0; kt < 32; ++kt) {
    const int cur = kt & 1;
    if (kt < 31) stage(cur ^ 1);

    f16x8 a[2];
#pragma unroll
    for (int i = 0; i < 2; ++i)
      a[i] = *(const f16x8*)&lds2[cur][(size_t)(kg * 128 + wv * 32 + i * 16 + lr) * 8];
#pragma unroll
    for (int j = 0; j < 4; ++j) {
      f16x8 bh = *(const f16x8*)&lds2[cur][4096 + (size_t)(kg * 64 + j * 16 + lr) * 8];
      f16x8 bl = *(const f16x8*)&lds2[cur][6144 + (size_t)(kg * 64 + j * 16 + lr) * 8];
#pragma unroll
      for (int i = 0; i < 2; ++i) {
        acch[i][j] = __builtin_amdgcn_mfma_f32_16x16x32_f16(a[i], bh, acch[i][j], 0, 0, 0);
        accl[i][j] = __builtin_amdgcn_mfma_f32_16x16x32_f16(a[i], bl, accl[i][j], 0, 0, 0);
      }
    }
    __syncthreads();
  }

  unsigned char* outs = outsbase + (size_t)z * B_ * H2_;
#pragma unroll
  for (int i = 0; i < 2; ++i)
#pragma unroll
    for (int j = 0; j < 4; ++j) {
      const int n = j * 16 + lr;
#pragma unroll
      for (int r = 0; r < 4; ++r) {
        const int m = m0 + wv * 32 + i * 16 + kg * 4 + r;
        float v = acch[i][j][r] + accl[i][j][r] * 4.8828125e-4f;
        outs[(size_t)m * H2_ + n] = (v >= 1.0f) ? 1 : 0;
      }
    }
}

// ---------------------------------------------------------------- attention + head
__global__ __launch_bounds__(256)
void final_kernel(const unsigned char* __restrict__ outsbase,
                  const float* __restrict__ postab,
                  const float* __restrict__ apw, const float* __restrict__ apb,
                  const float* __restrict__ anw, const float* __restrict__ anb,
                  const float* __restrict__ mtgw, const float* __restrict__ mtgb,
                  float* __restrict__ out)
{
  const int b = blockIdx.x * 4 + (threadIdx.x >> 6);
  const int lane = threadIdx.x & 63;
  float stacked = 0.f;
#pragma unroll
  for (int c = 0; c < 2; ++c) {
    const int Tc = c ? 4 : 8;
    const int zb = c ? 8 : 0;
    const float wp = apw[c * H2_ + lane];
    const float wn = anw[c * H2_ + lane];
    float seqv[8], sp[8], sn[8];
#pragma unroll
    for (int tt = 0; tt < Tc; ++tt) {
      const float sv = (float)outsbase[((size_t)(zb + tt) * B_ + b) * H2_ + lane];
      seqv[tt] = sv;
      sp[tt] = wsum64((sv + postab[tt * H2_ + lane]) * wp);
      sn[tt] = wsum64(sv * wn);
    }
    const float bp = apb[c], bn = anb[c];
    float mp = -3.4e38f, mn = -3.4e38f;
#pragma unroll
    for (int tt = 0; tt < Tc; ++tt) {
      sp[tt] += bp; sn[tt] += bn;
      mp = fmaxf(mp, sp[tt]); mn = fmaxf(mn, sn[tt]);
    }
    float ep[8], en[8], sump = 0.f, sumn = 0.f;
#pragma unroll
    for (int tt = 0; tt < Tc; ++tt) {
      ep[tt] = expf(sp[tt] - mp);
      en[tt] = expf(sn[tt] - mn);
      sump += ep[tt]; sumn += en[tt];
    }
    float embp = 0.f, embn = 0.f;
#pragma unroll
    for (int tt = 0; tt < Tc; ++tt) {
      embp += (seqv[tt] + postab[tt * H2_ + lane]) * (ep[tt] / sump);
      embn += seqv[tt] * (en[tt] / sumn);
    }
    stacked += 0.5f * (0.6f * embp + 0.4f * embn);
  }
  float res = 0.f;
#pragma unroll
  for (int o = 0; o < O_; ++o) {
    float r = wsum64(stacked * mtgw[lane * O_ + o]);
    if (lane == o) res = r;
  }
  if (lane < O_) out[(size_t)b * O_ + lane] = res + mtgb[lane];
}

// ---------------------------------------------------------------- launch
extern "C" void kernel_launch(void* const* d_in, const int* in_sizes, int n_in,
                              void* d_out, int out_size, void* d_ws, size_t ws_size,
                              hipStream_t stream)
{
  const int*   nodes  = (const int*)d_in[0];
  const int*   hop1   = (const int*)d_in[1];
  const int*   hop2   = (const int*)d_in[2];
  const float* x      = (const float*)d_in[3];
  const float* Wself1 = (const float*)d_in[4];
  const float* Wnbr1  = (const float*)d_in[5];
  const float* Wself2 = (const float*)d_in[6];
  const float* Wnbr2  = (const float*)d_in[7];
  const float* apw    = (const float*)d_in[8];
  const float* apb    = (const float*)d_in[9];
  const float* anw    = (const float*)d_in[10];
  const float* anb    = (const float*)d_in[11];
  const float* mtgw   = (const float*)d_in[12];
  const float* mtgb   = (const float*)d_in[13];
  float* out = (float*)d_out;

  char* ws = (char*)d_ws;
  size_t off = 0;
  float* postab = (float*)(ws + off);               off += 4096;
  f16* Ahb = (f16*)(ws + off);                      off += (size_t)T_ * M1 * K1 * 2;  // 100.66 MB
  f16* Alb = (f16*)(ws + off);                      off += (size_t)T_ * M1 * K1 * 2;  // 100.66 MB
  unsigned char* Sbase = (unsigned char*)(ws + off); off += (size_t)NZ * M1 * H1_;    // 151.0 MB
  unsigned char* outsb = (unsigned char*)(ws + off); off += (size_t)NZ * B_ * H2_;    //   3.1 MB
  if (ws_size < off) return;

  // stream-ordered aliases:
  //  - gemm1 B limbs live in outsb until gemm2 overwrites outs (1.0 MB < 3.1 MB)
  //  - A2 (12*4096*1024 f16) reuses Ahb after gemm1 (exact same size)
  //  - B2t limbs (512 KB) reuse Alb after gemm1
  f16* Bth = (f16*)outsb;
  f16* Btl = Bth + (size_t)2 * H1_ * K1;
  f16* A2  = Ahb;
  f16* B2h = Alb;
  f16* B2l = B2h + (size_t)2 * H2_ * 1024;

  hipLaunchKernelGGL(postab_kernel, dim3(1), dim3(512), 0, stream, postab);
  hipLaunchKernelGGL(prep_w, dim3(1024), dim3(256), 0, stream, Wself1, Wnbr1, Bth, Btl);
  hipLaunchKernelGGL(gather_kernel, dim3(M1 / 4, T_), dim3(256), 0, stream,
                     nodes, hop1, hop2, x, Ahb, Alb);
  hipLaunchKernelGGL(gemm1_mfma, dim3(4, M1 / 128, NZ), dim3(256), 0, stream,
                     Ahb, Alb, Bth, Btl, Sbase);
  hipLaunchKernelGGL(prep_w2, dim3(128), dim3(256), 0, stream, Wself2, Wnbr2, B2h, B2l);
  hipLaunchKernelGGL(prep_a2, dim3(B_ / 4, NZ), dim3(256), 0, stream, Sbase, A2);
  hipLaunchKernelGGL(gemm2_mfma, dim3(B_ / 128, NZ), dim3(256), 0, stream,
                     A2, B2h, B2l, outsb);
  hipLaunchKernelGGL(final_kernel, dim3(B_ / 4), dim3(256), 0, stream,
                     outsb, postab, apw, apb, anw, anb, mtgw, mtgb, out);
}